// Round 7
// baseline (1257.940 us; speedup 1.0000x reference)
//
#include <hip/hip_runtime.h>
#include <hip/hip_bf16.h>

// ---------------------------------------------------------------------------
// GCNEncoder: 3x (GCNConv -> [BN -> LeakyReLU]), N=50000 nodes, E=800000 edges.
//   Layer1 aggregate-first:  out1 = (A_hat X) W1 + b1
//   Layers2/3 transform-first: hd = (act(prev) @ W) * dinv; out = gather + bias
// R21: aggregation rewritten pull->push. R18/R20 showed wave-per-node agg is
// serial-latency-bound (~51.5us each, VALU 23%, HBM 7.6%): per-node chain
// rs->elist->shfl->gather x3 passes. New aggL_k: block owns 64 dst nodes,
// 64x65 f32 LDS accumulator; waves stream 16 edges/iter (independent iters,
// no chains); ds_add_f32 atomics; epilogue adds self-loop + bias + dinv.
// elist now stores the packed (src<<8|dst_local) record (fill2 1-line change).
// Rest = R17: radix CSR, int8 q rows, separate stat_k, merged setup+cnt.
// ---------------------------------------------------------------------------

#define LEAKY 0.01f
#define EPS_BN 1e-5f
#define NBIN 256
#define CB   128

typedef unsigned int uint32;

static __device__ __forceinline__ float bf_lo(uint32 u) { return __uint_as_float(u << 16); }
static __device__ __forceinline__ float bf_hi(uint32 u) { return __uint_as_float(u & 0xFFFF0000u); }

static __device__ __forceinline__ uint32 pack_bf(float x, float y) {
    __hip_bfloat16 bx = __float2bfloat16(x), by = __float2bfloat16(y);
    return (uint32)(*(unsigned short*)&bx) | ((uint32)(*(unsigned short*)&by) << 16);
}

// signed-byte extract -> float
static __device__ __forceinline__ float sb0(uint32 u) { return (float)((int)(u << 24) >> 24); }
static __device__ __forceinline__ float sb1(uint32 u) { return (float)((int)(u << 16) >> 24); }
static __device__ __forceinline__ float sb2(uint32 u) { return (float)((int)(u <<  8) >> 24); }
static __device__ __forceinline__ float sb3(uint32 u) { return (float)((int)u >> 24); }

// ---- merged: dtype detect + param convert (b<83) | zero stats (b==83) |
// ----         radix bin count (84..211)  -- all independent work ----------

__global__ __launch_bounds__(256) void setup_cnt_k(
    const uint32* __restrict__ x, int* __restrict__ flag,
    const void* p0, const void* p1, const void* p2, const void* p3,
    const void* p4, const void* p5, const void* p6, const void* p7,
    const void* p8, const void* p9, float* __restrict__ dst,
    float* __restrict__ stats1, float* __restrict__ stats2,
    const int* __restrict__ dstE, int* __restrict__ pbc, int E) {
    const int b = blockIdx.x, t = threadIdx.x;
    if (b < 83) {
        __shared__ int sd[256];
        int c = 0;
        for (int j = 0; j < 16; ++j) {
            uint32 w = x[t * 16 + j];
            uint32 m = w & 0x7FFFu;
            uint32 e = (w >> 7) & 0xFFu;
            if (m == 0u || (e >= 100u && e <= 150u)) ++c;
        }
        sd[t] = c;
        __syncthreads();
        for (int off = 128; off > 0; off >>= 1) {
            if (t < off) sd[t] += sd[t + off];
            __syncthreads();
        }
        bool bf = (sd[0] >= 3072);
        if (b == 0 && t == 0) *flag = bf ? 1 : 0;
        int i = b * 256 + t;
        if (i < 21120) {
            const void* p;
            int j;
            if      (i <  8192) { p = p0; j = i;         }
            else if (i <  8320) { p = p1; j = i - 8192;  }
            else if (i <  8448) { p = p2; j = i - 8320;  }
            else if (i <  8576) { p = p3; j = i - 8448;  }
            else if (i < 16768) { p = p4; j = i - 8576;  }
            else if (i < 16832) { p = p5; j = i - 16768; }
            else if (i < 16896) { p = p6; j = i - 16832; }
            else if (i < 16960) { p = p7; j = i - 16896; }
            else if (i < 21056) { p = p8; j = i - 16960; }
            else                { p = p9; j = i - 21056; }
            dst[i] = bf ? __bfloat162float(((const __hip_bfloat16*)p)[j])
                        : ((const float*)p)[j];
        }
    } else if (b == 83) {
        stats1[t] = 0.f;
        if (t < 128) stats2[t] = 0.f;
    } else {
        __shared__ int c[NBIN];
        c[t] = 0;
        __syncthreads();
        const int cb = b - 84;
        const int chunk = (E + CB - 1) / CB;
        const int lo = cb * chunk, hi = min(E, lo + chunk);
        for (int i = lo + t; i < hi; i += 256)
            atomicAdd(&c[dstE[i] >> 8], 1);
        __syncthreads();
        pbc[t * CB + cb] = c[t];
    }
}

// one block, 256 threads (thread j owns bin j); prefix over CB in registers.
__global__ __launch_bounds__(256) void scan2_k(int* __restrict__ pbc,
                                               int* __restrict__ bb,
                                               int* __restrict__ row_end, int E) {
    const int j = threadIdx.x;
    int4 vals[CB / 4];
    int tot = 0;
#pragma unroll
    for (int c = 0; c < CB / 4; ++c) {
        vals[c] = ((const int4*)(pbc + j * CB))[c];
        tot += vals[c].x + vals[c].y + vals[c].z + vals[c].w;
    }
    __shared__ int sd[NBIN];
    sd[j] = tot;
    __syncthreads();
    for (int off = 1; off < NBIN; off <<= 1) {
        int x = (j >= off) ? sd[j - off] : 0;
        __syncthreads();
        sd[j] += x;
        __syncthreads();
    }
    int run = sd[j] - tot;   // exclusive bucket base
    bb[j] = run;
    if (j == 0) *row_end = E;
#pragma unroll
    for (int c = 0; c < CB / 4; ++c) {
        int4 v = vals[c];
        int a0 = run; run += v.x;
        int a1 = run; run += v.y;
        int a2 = run; run += v.z;
        int a3 = run; run += v.w;
        ((int4*)(pbc + j * CB))[c] = make_int4(a0, a1, a2, a3);
    }
}

// packed edge record: (src << 8) | (dst & 255). bin implied by position.
__global__ __launch_bounds__(256) void scat_k(const int* __restrict__ src,
                                              const int* __restrict__ dst,
                                              const int* __restrict__ pbc,
                                              uint32* __restrict__ ebuf, int E) {
    __shared__ int cur[NBIN];
    cur[threadIdx.x] = pbc[threadIdx.x * CB + blockIdx.x];
    __syncthreads();
    const int chunk = (E + CB - 1) / CB;
    const int lo = blockIdx.x * chunk, hi = min(E, lo + chunk);
    for (int i = lo + threadIdx.x; i < hi; i += 256) {
        int d = dst[i];
        int p = atomicAdd(&cur[d >> 8], 1);      // LDS atomic
        ebuf[p] = ((uint32)src[i] << 8) | (uint32)(d & 255);
    }
}

// one block per bin (256 nodes): CSR rows + elist (packed records, CSR-sorted)
// + int8 per-row quantized xs (dinv folded into scale) + dinv.
__global__ __launch_bounds__(256) void fill2_k(
    const uint32* __restrict__ ebuf, const int* __restrict__ bb,
    int* __restrict__ row_start, uint32* __restrict__ elist,
    const void* __restrict__ xv, const int* __restrict__ flag,
    uint32* __restrict__ q, float* __restrict__ qs, float* __restrict__ dinv,
    int n) {
    __shared__ int cntl[NBIN], curl[NBIN], sd[NBIN];
    const int j = blockIdx.x, t = threadIdx.x;
    const int lo = j << 8;
    const int hi = min(n, lo + 256);
    const int nn = hi - lo;
    if (nn <= 0) return;
    const int eb = bb[j], ee = bb[j + 1];

    cntl[t] = 0;
    __syncthreads();
    for (int i = eb + t; i < ee; i += 256)
        atomicAdd(&cntl[ebuf[i] & 255u], 1);     // LDS atomic
    __syncthreads();
    int cv = cntl[t];
    sd[t] = cv;
    __syncthreads();
    for (int off = 1; off < NBIN; off <<= 1) {
        int x = (t >= off) ? sd[t - off] : 0;
        __syncthreads();
        sd[t] += x;
        __syncthreads();
    }
    int pref = sd[t] - cv;                        // exclusive
    if (t < nn) row_start[lo + t] = eb + pref;
    curl[t] = pref;
    __syncthreads();
    for (int i = eb + t; i < ee; i += 256) {
        uint32 e = ebuf[i];
        int p = atomicAdd(&curl[e & 255u], 1);    // LDS atomic
        elist[eb + p] = e;                        // keep packed (src<<8|dl)
    }
    // per-thread node row: quantize x*dinv to int8 with per-row scale
    const int v = lo + t;
    if (v < hi) {
        const bool bf = (*flag != 0);
        float d = rsqrtf((float)(cntl[t] + 1));
        dinv[v] = d;
        float vals[64];
        if (bf) {
#pragma unroll
            for (int c = 0; c < 16; ++c) {
                uint2 u = ((const uint2*)xv)[(size_t)v * 16 + c];
                vals[4 * c + 0] = bf_lo(u.x); vals[4 * c + 1] = bf_hi(u.x);
                vals[4 * c + 2] = bf_lo(u.y); vals[4 * c + 3] = bf_hi(u.y);
            }
        } else {
#pragma unroll
            for (int c = 0; c < 16; ++c) {
                float4 f = ((const float4*)xv)[(size_t)v * 16 + c];
                vals[4 * c + 0] = f.x; vals[4 * c + 1] = f.y;
                vals[4 * c + 2] = f.z; vals[4 * c + 3] = f.w;
            }
        }
        float rm = 0.f;
#pragma unroll
        for (int i = 0; i < 64; ++i) rm = fmaxf(rm, fabsf(vals[i]));
        float inv = (rm > 0.f) ? 127.0f / rm : 0.f;
#pragma unroll
        for (int c = 0; c < 16; ++c) {
            int b0 = (int)rintf(vals[4 * c + 0] * inv);
            int b1 = (int)rintf(vals[4 * c + 1] * inv);
            int b2 = (int)rintf(vals[4 * c + 2] * inv);
            int b3 = (int)rintf(vals[4 * c + 3] * inv);
            q[(size_t)v * 16 + c] = (uint32)(b0 & 0xFF) | ((uint32)(b1 & 0xFF) << 8) |
                                    ((uint32)(b2 & 0xFF) << 16) | ((uint32)(b3 & 0xFF) << 24);
        }
        qs[v] = d * rm * (1.0f / 127.0f);   // dinv folded into scale
    }
}

// ---------------- aggregation: edge-streaming push into LDS ----------------
// Block owns 64 consecutive dst nodes; acc[ch][node] (65-pad) f32 in LDS.
// Waves stream 16 edges/iter: lane L -> edge el=L>>2 of the group, 16B chunk
// c=L&3 of the 64B int8 row (channels c*16..c*16+15). ds_add_f32 atomics;
// iterations are independent -> VMEM pipelines freely (no per-node chains).
// Epilogue: thread t -> node t&63, channel quarter t>>6: self-loop term +
// dinv scale + bias, bf16 (2x uint4) or f32 (4x float4) store.

template <bool BIAS, bool OUT_NATIVE>
__global__ __launch_bounds__(256) void aggL_k(
    const uint32* __restrict__ q, const float* __restrict__ qs,
    const float* __restrict__ dinv, const int* __restrict__ row_start,
    const uint32* __restrict__ elist, const float* __restrict__ bias,
    void* __restrict__ outv, const int* __restrict__ flag, int n) {
    __shared__ float acc[64 * 65];
    const int tid = threadIdx.x;
    const int g0 = blockIdx.x * 64;             // first node of group
    const int nn = min(64, n - g0);             // nodes in group
    const int bl = g0 & 255;                    // group's dst_local base in bin
    const int eb = row_start[g0];
    const int ee = row_start[min(g0 + 64, n)];  // row_start[n] = E

    for (int i = tid; i < 64 * 65; i += 256) acc[i] = 0.f;
    __syncthreads();

    const uint4* __restrict__ q4 = (const uint4*)q;
    const int w  = tid >> 6;
    const int L  = tid & 63;
    const int el = L >> 2;      // edge slot 0..15
    const int c  = L & 3;       // 16B chunk of row

    for (int i0 = eb + w * 16; i0 < ee; i0 += 64) {
        const int idx = i0 + el;
        const uint32 e = elist[min(idx, ee - 1)];
        const int src = (int)(e >> 8);
        const int nl  = (int)(e & 255u) - bl;   // 0..63
        const float sc = (idx < ee) ? qs[src] : 0.f;
        const uint4 u = q4[(size_t)src * 4 + c];
        float* a = &acc[c * 16 * 65 + nl];
        atomicAdd(a + 0 * 65, sc * sb0(u.x));
        atomicAdd(a + 1 * 65, sc * sb1(u.x));
        atomicAdd(a + 2 * 65, sc * sb2(u.x));
        atomicAdd(a + 3 * 65, sc * sb3(u.x));
        atomicAdd(a + 4 * 65, sc * sb0(u.y));
        atomicAdd(a + 5 * 65, sc * sb1(u.y));
        atomicAdd(a + 6 * 65, sc * sb2(u.y));
        atomicAdd(a + 7 * 65, sc * sb3(u.y));
        atomicAdd(a + 8 * 65, sc * sb0(u.z));
        atomicAdd(a + 9 * 65, sc * sb1(u.z));
        atomicAdd(a + 10 * 65, sc * sb2(u.z));
        atomicAdd(a + 11 * 65, sc * sb3(u.z));
        atomicAdd(a + 12 * 65, sc * sb0(u.w));
        atomicAdd(a + 13 * 65, sc * sb1(u.w));
        atomicAdd(a + 14 * 65, sc * sb2(u.w));
        atomicAdd(a + 15 * 65, sc * sb3(u.w));
    }
    __syncthreads();

    // epilogue: node v = g0 + (tid&63), channels qd*16..qd*16+15
    const int nl2 = tid & 63, qd = tid >> 6;
    const int v = g0 + nl2;
    if (nl2 < nn) {
        const float dv = dinv[v];
        const float ssc = qs[v];
        const uint4 su = q4[(size_t)v * 4 + qd];
        float o[16];
        const uint32 wd[4] = {su.x, su.y, su.z, su.w};
#pragma unroll
        for (int wi = 0; wi < 4; ++wi) {
            const int ch = qd * 16 + wi * 4;
            o[wi * 4 + 0] = acc[(ch + 0) * 65 + nl2] + ssc * sb0(wd[wi]);
            o[wi * 4 + 1] = acc[(ch + 1) * 65 + nl2] + ssc * sb1(wd[wi]);
            o[wi * 4 + 2] = acc[(ch + 2) * 65 + nl2] + ssc * sb2(wd[wi]);
            o[wi * 4 + 3] = acc[(ch + 3) * 65 + nl2] + ssc * sb3(wd[wi]);
        }
        float b[16];
#pragma unroll
        for (int i = 0; i < 16; ++i) b[i] = 0.f;
        if constexpr (BIAS) {
#pragma unroll
            for (int wi = 0; wi < 4; ++wi) {
                float4 bv = ((const float4*)bias)[qd * 4 + wi];
                b[wi * 4 + 0] = bv.x; b[wi * 4 + 1] = bv.y;
                b[wi * 4 + 2] = bv.z; b[wi * 4 + 3] = bv.w;
            }
        }
#pragma unroll
        for (int i = 0; i < 16; ++i) o[i] = fmaf(dv, o[i], b[i]);
        bool f32out = false;
        if constexpr (OUT_NATIVE) f32out = (*flag == 0);
        if (f32out) {
#pragma unroll
            for (int wi = 0; wi < 4; ++wi)
                ((float4*)outv)[(size_t)v * 16 + qd * 4 + wi] =
                    make_float4(o[wi * 4 + 0], o[wi * 4 + 1], o[wi * 4 + 2], o[wi * 4 + 3]);
        } else {
            ((uint4*)outv)[(size_t)v * 8 + qd * 2 + 0] =
                make_uint4(pack_bf(o[0], o[1]), pack_bf(o[2], o[3]),
                           pack_bf(o[4], o[5]), pack_bf(o[6], o[7]));
            ((uint4*)outv)[(size_t)v * 8 + qd * 2 + 1] =
                make_uint4(pack_bf(o[8], o[9]), pack_bf(o[10], o[11]),
                           pack_bf(o[12], o[13]), pack_bf(o[14], o[15]));
        }
    }
}

// ---------------- BN stats over bf16 [n,C] buffer ----------------
// uint2 per lane (4 channels); 256 blocks (small atomic fan-in).

template <int C2>
__global__ __launch_bounds__(256) void stat_k(const uint2* __restrict__ buf,
                                              float* __restrict__ stats, int n) {
    constexpr int LPR = C2 / 2;      // lanes per row
    constexpr int RPB = 256 / LPR;   // rows per block-iteration
    constexpr int C = 2 * C2;
    const int lp = threadIdx.x % LPR;
    const int rg = threadIdx.x / LPR;
    float s0 = 0.f, s1 = 0.f, s2 = 0.f, s3 = 0.f;
    float q0 = 0.f, q1 = 0.f, q2 = 0.f, q3 = 0.f;
    for (int r = blockIdx.x * RPB + rg; r < n; r += gridDim.x * RPB) {
        uint2 u = buf[(size_t)r * LPR + lp];
        float f0 = bf_lo(u.x), f1 = bf_hi(u.x);
        float f2 = bf_lo(u.y), f3 = bf_hi(u.y);
        s0 += f0; q0 = fmaf(f0, f0, q0);
        s1 += f1; q1 = fmaf(f1, f1, q1);
        s2 += f2; q2 = fmaf(f2, f2, q2);
        s3 += f3; q3 = fmaf(f3, f3, q3);
    }
    __shared__ float sd[2 * C];
    for (int i = threadIdx.x; i < 2 * C; i += 256) sd[i] = 0.f;
    __syncthreads();
    atomicAdd(&sd[4 * lp + 0], s0);
    atomicAdd(&sd[4 * lp + 1], s1);
    atomicAdd(&sd[4 * lp + 2], s2);
    atomicAdd(&sd[4 * lp + 3], s3);
    atomicAdd(&sd[C + 4 * lp + 0], q0);
    atomicAdd(&sd[C + 4 * lp + 1], q1);
    atomicAdd(&sd[C + 4 * lp + 2], q2);
    atomicAdd(&sd[C + 4 * lp + 3], q3);
    __syncthreads();
    for (int i = threadIdx.x; i < 2 * C; i += 256) atomicAdd(&stats[i], sd[i]);
}

// ---------------- GEMM: out = epilogue( act(A) @ W ) ----------------
// A [n,K] bf16 flat, W [K,N] f32. XOR-swizzled Ast staging.
// AFFS: in-block BN coefs from raw stats. BIAS: +bias[col]. DINV: row scale.
// QUANT (requires N=64, CG=16, DINV): int8 per-row output via 16-lane
// shfl-max (row spans lanes tc=0..15 of one wave subgroup) -> q + qs.

template <int K, int N, int MR, bool AFFS, bool BIAS, bool DINV, bool QUANT>
__global__ __launch_bounds__(256) void gemm_k(
    const __hip_bfloat16* __restrict__ A, const float* __restrict__ W,
    const float* __restrict__ stats, const float* __restrict__ g,
    const float* __restrict__ be, float invN,
    const float* __restrict__ bias, const float* __restrict__ dinv,
    __hip_bfloat16* __restrict__ out, uint32* __restrict__ qout,
    float* __restrict__ qscale, int n) {
    constexpr int CG = N / 4;        // threads across columns
    constexpr int RG = 256 / CG;     // row groups
    constexpr int TM = RG * MR;      // rows per block
    __shared__ __align__(16) float Ws[K * N];
    __shared__ __align__(16) float Ast[K * TM];
    __shared__ float cf[AFFS ? 2 * K : 1];

    const int tid = threadIdx.x;
    if constexpr (AFFS) {
        if (tid < K) {
            float mean = stats[tid] * invN;
            float var  = fmaxf(fmaf(-mean, mean, stats[K + tid] * invN), 0.f);
            float a    = g[tid] * rsqrtf(var + EPS_BN);
            cf[tid]     = a;
            cf[K + tid] = be[tid] - mean * a;
        }
        __syncthreads();
    }

    for (int i = tid; i < K * N / 4; i += 256)
        ((float4*)Ws)[i] = ((const float4*)W)[i];

    const int row0 = blockIdx.x * TM;
    constexpr int KC = K / 4;
    for (int i = tid; i < TM * KC; i += 256) {
        int r  = i / KC;
        int c4 = (i - r * KC) * 4;
        int gr = row0 + r;
        float f0 = 0.f, f1 = 0.f, f2 = 0.f, f3 = 0.f;
        if (gr < n) {
            uint2 u = *(const uint2*)(A + (size_t)gr * K + c4);
            f0 = bf_lo(u.x); f1 = bf_hi(u.x);
            f2 = bf_lo(u.y); f3 = bf_hi(u.y);
            if constexpr (AFFS) {
                f0 = fmaf(cf[c4 + 0], f0, cf[K + c4 + 0]); f0 = f0 > 0.f ? f0 : LEAKY * f0;
                f1 = fmaf(cf[c4 + 1], f1, cf[K + c4 + 1]); f1 = f1 > 0.f ? f1 : LEAKY * f1;
                f2 = fmaf(cf[c4 + 2], f2, cf[K + c4 + 2]); f2 = f2 > 0.f ? f2 : LEAKY * f2;
                f3 = fmaf(cf[c4 + 3], f3, cf[K + c4 + 3]); f3 = f3 > 0.f ? f3 : LEAKY * f3;
            }
        }
        const int rr = r ^ (4 * ((c4 >> 2) & 7));
        Ast[(c4 + 0) * TM + rr] = f0;
        Ast[(c4 + 1) * TM + rr] = f1;
        Ast[(c4 + 2) * TM + rr] = f2;
        Ast[(c4 + 3) * TM + rr] = f3;
    }
    __syncthreads();

    const int tr = tid / CG, tc = tid % CG;
    float acc[MR][4];
#pragma unroll
    for (int m = 0; m < MR; ++m)
#pragma unroll
        for (int j = 0; j < 4; ++j) acc[m][j] = 0.f;

#pragma unroll 4
    for (int k = 0; k < K; ++k) {
        float4 w = *(const float4*)&Ws[k * N + tc * 4];
        const int sk = 4 * ((k >> 2) & 7);
        float am[MR];
        if constexpr (MR == 4) {
            float4 t = *(const float4*)&Ast[k * TM + ((tr * 4) ^ sk)];
            am[0] = t.x; am[1] = t.y; am[2] = t.z; am[3] = t.w;
        } else {
            float2 t = *(const float2*)&Ast[k * TM + ((tr * 2) ^ sk)];
            am[0] = t.x; am[1] = t.y;
        }
#pragma unroll
        for (int m = 0; m < MR; ++m) {
            acc[m][0] = fmaf(am[m], w.x, acc[m][0]);
            acc[m][1] = fmaf(am[m], w.y, acc[m][1]);
            acc[m][2] = fmaf(am[m], w.z, acc[m][2]);
            acc[m][3] = fmaf(am[m], w.w, acc[m][3]);
        }
    }

    float bv[4] = {0.f, 0.f, 0.f, 0.f};
    if constexpr (BIAS) {
#pragma unroll
        for (int j = 0; j < 4; ++j) bv[j] = bias[tc * 4 + j];
    }

#pragma unroll
    for (int m = 0; m < MR; ++m) {
        int gr = row0 + tr * MR + m;
        float sc = 1.f;
        if constexpr (DINV) sc = (gr < n) ? dinv[gr] : 0.f;
        float val[4];
#pragma unroll
        for (int j = 0; j < 4; ++j) {
            float v = acc[m][j];
            if constexpr (BIAS) v += bv[j];
            else                v *= sc;
            val[j] = v;
        }
        if constexpr (QUANT) {
            // row gr spans lanes tc=0..15 of this 16-lane subgroup
            float rm = fmaxf(fmaxf(fabsf(val[0]), fabsf(val[1])),
                             fmaxf(fabsf(val[2]), fabsf(val[3])));
            rm = fmaxf(rm, __shfl_xor(rm, 1));
            rm = fmaxf(rm, __shfl_xor(rm, 2));
            rm = fmaxf(rm, __shfl_xor(rm, 4));
            rm = fmaxf(rm, __shfl_xor(rm, 8));
            float inv = (rm > 0.f) ? 127.0f / rm : 0.f;
            if (gr < n) {
                int b0 = (int)rintf(val[0] * inv);
                int b1 = (int)rintf(val[1] * inv);
                int b2 = (int)rintf(val[2] * inv);
                int b3 = (int)rintf(val[3] * inv);
                qout[(size_t)gr * 16 + tc] =
                    (uint32)(b0 & 0xFF) | ((uint32)(b1 & 0xFF) << 8) |
                    ((uint32)(b2 & 0xFF) << 16) | ((uint32)(b3 & 0xFF) << 24);
                if (tc == 0) qscale[gr] = rm * (1.0f / 127.0f);
            }
        } else {
            if (gr < n) {
                __attribute__((aligned(8))) __hip_bfloat16 pk[4];
#pragma unroll
                for (int j = 0; j < 4; ++j) pk[j] = __float2bfloat16(val[j]);
                *(uint2*)(out + (size_t)gr * N + tc * 4) = *(const uint2*)pk;
            }
        }
    }
}

// ---------------- host ----------------

extern "C" void kernel_launch(void* const* d_in, const int* in_sizes, int n_in,
                              void* d_out, int out_size, void* d_ws, size_t ws_size,
                              hipStream_t stream) {
    const int n = in_sizes[0] / 64;   // 50000
    const int E = in_sizes[1] / 2;    // 800000

    const void* x  = d_in[0];
    const int*  ei = (const int*)d_in[1];

    // workspace carve (256B aligned) — total ~30 MB
    char* w = (char*)d_ws;
    auto alloc = [&](size_t bytes) -> void* {
        void* p = (void*)w;
        w += (bytes + 255) & ~(size_t)255;
        return p;
    };
    int*   flag      = (int*)alloc(256);
    float* Wf        = (float*)alloc(21120 * 4);            // converted params
    int*   pbc       = (int*)alloc((size_t)CB * NBIN * 4);
    int*   bb        = (int*)alloc((NBIN + 2) * 4);
    int*   row_start = (int*)alloc((size_t)(n + 1) * 4);
    uint32* elist    = (uint32*)alloc((size_t)E * 4);       // packed CSR records
    uint32* ebuf     = (uint32*)alloc((size_t)E * 4);       // packed (src<<8)|dl
    float* dinv      = (float*)alloc((size_t)n * 4);
    float* stats1    = (float*)alloc(256 * 4);
    float* stats2    = (float*)alloc(128 * 4);
    uint32* q        = (uint32*)alloc((size_t)n * 16 * 4);  // int8 rows (xs/hd2/hd3)
    float*  qsA      = (float*)alloc((size_t)n * 4);        // per-row scales
    __hip_bfloat16* B1 = (__hip_bfloat16*)alloc((size_t)n * 64 * 2);   // AX (bf16)
    __hip_bfloat16* B2 = (__hip_bfloat16*)alloc((size_t)n * 128 * 2);  // out1 / out2

    // param offsets inside Wf
    float* W1f = Wf + 0;     float* b1f = Wf + 8192;
    float* g1f = Wf + 8320;  float* be1f = Wf + 8448;
    float* W2f = Wf + 8576;  float* b2f = Wf + 16768;
    float* g2f = Wf + 16832; float* be2f = Wf + 16896;
    float* W3f = Wf + 16960; float* b3f = Wf + 21056;

    const float invN = 1.0f / (float)n;
    const int nbins = (n + 255) >> 8;        // bins of 256 nodes
    const int agb   = (n + 63) / 64;         // 64-node groups for aggL

    // 1: detect + cvt params + zero stats + bin count (merged, independent)
    setup_cnt_k<<<212, 256, 0, stream>>>((const uint32*)x, flag,
        d_in[2], d_in[3], d_in[4], d_in[5], d_in[6], d_in[7], d_in[8], d_in[9],
        d_in[10], d_in[11], Wf, stats1, stats2, ei + E, pbc, E);
    // 2-4: atomic-free radix CSR build + int8 xs (dinv-folded scales)
    scan2_k<<<1, 256, 0, stream>>>(pbc, bb, row_start + n, E);
    scat_k<<<CB, 256, 0, stream>>>(ei, ei + E, pbc, ebuf, E);
    fill2_k<<<nbins, 256, 0, stream>>>(ebuf, bb, row_start, elist, x, flag,
                                       q, qsA, dinv, n);

    // Layer 1 (aggregate-first): B1 = A_hat x ; out1(B2) = B1@W1 + b1 ; stats1
    aggL_k<false, false><<<agb, 256, 0, stream>>>(q, qsA, dinv, row_start, elist,
                                                  nullptr, B1, flag, n);
    gemm_k<64, 128, 4, false, true, false, false><<<(n + 31) / 32, 256, 0, stream>>>(
        B1, W1f, nullptr, nullptr, nullptr, 0.f, b1f, nullptr, B2, nullptr, nullptr, n);
    stat_k<64><<<256, 256, 0, stream>>>((const uint2*)B2, stats1, n);

    // Layer 2: q = int8( (BN+leaky(out1)@W2)*dinv ) ; out2(B2) = gather + b2 ; stats2
    gemm_k<128, 64, 4, true, false, true, true><<<(n + 63) / 64, 256, 0, stream>>>(
        B2, W2f, stats1, g1f, be1f, invN, nullptr, dinv, nullptr, q, qsA, n);
    aggL_k<true, false><<<agb, 256, 0, stream>>>(q, qsA, dinv, row_start, elist,
                                                 b2f, B2, flag, n);
    stat_k<32><<<256, 256, 0, stream>>>((const uint2*)B2, stats2, n);

    // Layer 3: q = int8( (BN+leaky(out2)@W3)*dinv ) ; out = gather + b3 (native)
    gemm_k<64, 64, 4, true, false, true, true><<<(n + 63) / 64, 256, 0, stream>>>(
        B2, W3f, stats2, g2f, be2f, invN, nullptr, dinv, nullptr, q, qsA, n);
    aggL_k<true, true><<<agb, 256, 0, stream>>>(q, qsA, dinv, row_start, elist,
                                                b3f, d_out, flag, n);
}

// Round 8
// 337.083 us; speedup vs baseline: 3.7318x; 3.7318x over previous
//
#include <hip/hip_runtime.h>
#include <hip/hip_bf16.h>

// ---------------------------------------------------------------------------
// GCNEncoder: 3x (GCNConv -> [BN -> LeakyReLU]), N=50000 nodes, E=800000 edges.
//   Layer1 aggregate-first:  out1 = (A_hat X) W1 + b1
//   Layers2/3 transform-first: hd = (act(prev) @ W) * dinv; out = gather + bias
// R22: revert R21 push-agg (348us: CSR-sorted edges -> same-address LDS atomic
// serialization). Back to pull, but with WIDE gathers: lane covers 16B (uint4)
// of the 64B int8 row; one gather instr = 16 edges. Per node: 2 unconditional
// gathers cover 32 edges (94% of nodes) in ONE latency round + conditional
// second window. Agg VMEM instrs ~2.5x fewer than R17. 4-step butterfly.
// Kept: merged setup+cnt, packed ebuf, radix CSR, int8 q rows, stat_k, gemm.
// ---------------------------------------------------------------------------

#define LEAKY 0.01f
#define EPS_BN 1e-5f
#define NBIN 256
#define CB   128

typedef unsigned int uint32;

static __device__ __forceinline__ float bf_lo(uint32 u) { return __uint_as_float(u << 16); }
static __device__ __forceinline__ float bf_hi(uint32 u) { return __uint_as_float(u & 0xFFFF0000u); }

static __device__ __forceinline__ uint32 pack_bf(float x, float y) {
    __hip_bfloat16 bx = __float2bfloat16(x), by = __float2bfloat16(y);
    return (uint32)(*(unsigned short*)&bx) | ((uint32)(*(unsigned short*)&by) << 16);
}

// signed-byte extract -> float
static __device__ __forceinline__ float sb0(uint32 u) { return (float)((int)(u << 24) >> 24); }
static __device__ __forceinline__ float sb1(uint32 u) { return (float)((int)(u << 16) >> 24); }
static __device__ __forceinline__ float sb2(uint32 u) { return (float)((int)(u <<  8) >> 24); }
static __device__ __forceinline__ float sb3(uint32 u) { return (float)((int)u >> 24); }

// ---- merged: dtype detect + param convert (b<83) | zero stats (b==83) |
// ----         radix bin count (84..211)  -- all independent work ----------

__global__ __launch_bounds__(256) void setup_cnt_k(
    const uint32* __restrict__ x, int* __restrict__ flag,
    const void* p0, const void* p1, const void* p2, const void* p3,
    const void* p4, const void* p5, const void* p6, const void* p7,
    const void* p8, const void* p9, float* __restrict__ dst,
    float* __restrict__ stats1, float* __restrict__ stats2,
    const int* __restrict__ dstE, int* __restrict__ pbc, int E) {
    const int b = blockIdx.x, t = threadIdx.x;
    if (b < 83) {
        __shared__ int sd[256];
        int c = 0;
        for (int j = 0; j < 16; ++j) {
            uint32 w = x[t * 16 + j];
            uint32 m = w & 0x7FFFu;
            uint32 e = (w >> 7) & 0xFFu;
            if (m == 0u || (e >= 100u && e <= 150u)) ++c;
        }
        sd[t] = c;
        __syncthreads();
        for (int off = 128; off > 0; off >>= 1) {
            if (t < off) sd[t] += sd[t + off];
            __syncthreads();
        }
        bool bf = (sd[0] >= 3072);
        if (b == 0 && t == 0) *flag = bf ? 1 : 0;
        int i = b * 256 + t;
        if (i < 21120) {
            const void* p;
            int j;
            if      (i <  8192) { p = p0; j = i;         }
            else if (i <  8320) { p = p1; j = i - 8192;  }
            else if (i <  8448) { p = p2; j = i - 8320;  }
            else if (i <  8576) { p = p3; j = i - 8448;  }
            else if (i < 16768) { p = p4; j = i - 8576;  }
            else if (i < 16832) { p = p5; j = i - 16768; }
            else if (i < 16896) { p = p6; j = i - 16832; }
            else if (i < 16960) { p = p7; j = i - 16896; }
            else if (i < 21056) { p = p8; j = i - 16960; }
            else                { p = p9; j = i - 21056; }
            dst[i] = bf ? __bfloat162float(((const __hip_bfloat16*)p)[j])
                        : ((const float*)p)[j];
        }
    } else if (b == 83) {
        stats1[t] = 0.f;
        if (t < 128) stats2[t] = 0.f;
    } else {
        __shared__ int c[NBIN];
        c[t] = 0;
        __syncthreads();
        const int cb = b - 84;
        const int chunk = (E + CB - 1) / CB;
        const int lo = cb * chunk, hi = min(E, lo + chunk);
        for (int i = lo + t; i < hi; i += 256)
            atomicAdd(&c[dstE[i] >> 8], 1);
        __syncthreads();
        pbc[t * CB + cb] = c[t];
    }
}

// one block, 256 threads (thread j owns bin j); prefix over CB in registers.
__global__ __launch_bounds__(256) void scan2_k(int* __restrict__ pbc,
                                               int* __restrict__ bb,
                                               int* __restrict__ row_end, int E) {
    const int j = threadIdx.x;
    int4 vals[CB / 4];
    int tot = 0;
#pragma unroll
    for (int c = 0; c < CB / 4; ++c) {
        vals[c] = ((const int4*)(pbc + j * CB))[c];
        tot += vals[c].x + vals[c].y + vals[c].z + vals[c].w;
    }
    __shared__ int sd[NBIN];
    sd[j] = tot;
    __syncthreads();
    for (int off = 1; off < NBIN; off <<= 1) {
        int x = (j >= off) ? sd[j - off] : 0;
        __syncthreads();
        sd[j] += x;
        __syncthreads();
    }
    int run = sd[j] - tot;   // exclusive bucket base
    bb[j] = run;
    if (j == 0) *row_end = E;
#pragma unroll
    for (int c = 0; c < CB / 4; ++c) {
        int4 v = vals[c];
        int a0 = run; run += v.x;
        int a1 = run; run += v.y;
        int a2 = run; run += v.z;
        int a3 = run; run += v.w;
        ((int4*)(pbc + j * CB))[c] = make_int4(a0, a1, a2, a3);
    }
}

// packed edge record: (src << 8) | (dst & 255). bin implied by position.
__global__ __launch_bounds__(256) void scat_k(const int* __restrict__ src,
                                              const int* __restrict__ dst,
                                              const int* __restrict__ pbc,
                                              uint32* __restrict__ ebuf, int E) {
    __shared__ int cur[NBIN];
    cur[threadIdx.x] = pbc[threadIdx.x * CB + blockIdx.x];
    __syncthreads();
    const int chunk = (E + CB - 1) / CB;
    const int lo = blockIdx.x * chunk, hi = min(E, lo + chunk);
    for (int i = lo + threadIdx.x; i < hi; i += 256) {
        int d = dst[i];
        int p = atomicAdd(&cur[d >> 8], 1);      // LDS atomic
        ebuf[p] = ((uint32)src[i] << 8) | (uint32)(d & 255);
    }
}

// one block per bin (256 nodes): CSR rows + elist (src ids, L2-local window) +
// int8 per-row quantized xs (dinv folded into scale) + dinv.
__global__ __launch_bounds__(256) void fill2_k(
    const uint32* __restrict__ ebuf, const int* __restrict__ bb,
    int* __restrict__ row_start, int* __restrict__ elist,
    const void* __restrict__ xv, const int* __restrict__ flag,
    uint32* __restrict__ q, float* __restrict__ qs, float* __restrict__ dinv,
    int n) {
    __shared__ int cntl[NBIN], curl[NBIN], sd[NBIN];
    const int j = blockIdx.x, t = threadIdx.x;
    const int lo = j << 8;
    const int hi = min(n, lo + 256);
    const int nn = hi - lo;
    if (nn <= 0) return;
    const int eb = bb[j], ee = bb[j + 1];

    cntl[t] = 0;
    __syncthreads();
    for (int i = eb + t; i < ee; i += 256)
        atomicAdd(&cntl[ebuf[i] & 255u], 1);     // LDS atomic
    __syncthreads();
    int cv = cntl[t];
    sd[t] = cv;
    __syncthreads();
    for (int off = 1; off < NBIN; off <<= 1) {
        int x = (t >= off) ? sd[t - off] : 0;
        __syncthreads();
        sd[t] += x;
        __syncthreads();
    }
    int pref = sd[t] - cv;                        // exclusive
    if (t < nn) row_start[lo + t] = eb + pref;
    curl[t] = pref;
    __syncthreads();
    for (int i = eb + t; i < ee; i += 256) {
        uint32 e = ebuf[i];
        int p = atomicAdd(&curl[e & 255u], 1);    // LDS atomic
        elist[eb + p] = (int)(e >> 8);
    }
    // per-thread node row: quantize x*dinv to int8 with per-row scale
    const int v = lo + t;
    if (v < hi) {
        const bool bf = (*flag != 0);
        float d = rsqrtf((float)(cntl[t] + 1));
        dinv[v] = d;
        float vals[64];
        if (bf) {
#pragma unroll
            for (int c = 0; c < 16; ++c) {
                uint2 u = ((const uint2*)xv)[(size_t)v * 16 + c];
                vals[4 * c + 0] = bf_lo(u.x); vals[4 * c + 1] = bf_hi(u.x);
                vals[4 * c + 2] = bf_lo(u.y); vals[4 * c + 3] = bf_hi(u.y);
            }
        } else {
#pragma unroll
            for (int c = 0; c < 16; ++c) {
                float4 f = ((const float4*)xv)[(size_t)v * 16 + c];
                vals[4 * c + 0] = f.x; vals[4 * c + 1] = f.y;
                vals[4 * c + 2] = f.z; vals[4 * c + 3] = f.w;
            }
        }
        float rm = 0.f;
#pragma unroll
        for (int i = 0; i < 64; ++i) rm = fmaxf(rm, fabsf(vals[i]));
        float inv = (rm > 0.f) ? 127.0f / rm : 0.f;
#pragma unroll
        for (int c = 0; c < 16; ++c) {
            int b0 = (int)rintf(vals[4 * c + 0] * inv);
            int b1 = (int)rintf(vals[4 * c + 1] * inv);
            int b2 = (int)rintf(vals[4 * c + 2] * inv);
            int b3 = (int)rintf(vals[4 * c + 3] * inv);
            q[(size_t)v * 16 + c] = (uint32)(b0 & 0xFF) | ((uint32)(b1 & 0xFF) << 8) |
                                    ((uint32)(b2 & 0xFF) << 16) | ((uint32)(b3 & 0xFF) << 24);
        }
        qs[v] = d * rm * (1.0f / 127.0f);   // dinv folded into scale
    }
}

// ---------------- aggregation: wide-gather pull, one wave/node -------------
// q: [n][16] uint32, qs: per-row scale (layer1: includes dinv_src).
// Lane c=L&3 covers a 16B uint4 chunk (16 ch); slot=L>>2 is the edge 0..15.
// ONE gather instr covers 16 edges. Per 64-edge window: 2 unconditional
// gathers (32 edges, covers 94% of nodes, single latency round) + conditional
// 2 more. Clamped slots all hit the re-1 line (hot). 4-step butterfly
// (xor 4,8,16,32) reduces slots; epilogue on 4 lanes (c=chunk), wide stores.

template <bool BIAS, bool OUT_NATIVE>
__global__ __launch_bounds__(256) void agg_k(
    const uint32* __restrict__ q, const float* __restrict__ qs,
    const float* __restrict__ dinv, const int* __restrict__ row_start,
    const int* __restrict__ elist, const float* __restrict__ bias,
    void* __restrict__ outv, const int* __restrict__ flag, int n) {
    const int v = blockIdx.x * 4 + (threadIdx.x >> 6);
    if (v >= n) return;
    const int L    = threadIdx.x & 63;
    const int slot = L >> 2;   // edge slot 0..15
    const int c    = L & 3;    // uint4 chunk of 64B row (channels c*16..+15)

    const int rs = row_start[v], re = row_start[v + 1];
    const float dv = dinv[v];
    const uint4* __restrict__ q4 = (const uint4*)q;

    float acc[16];
#pragma unroll
    for (int i = 0; i < 16; ++i) acc[i] = 0.f;

    // self-loop on slot-0 lanes (lanes 0..3 cover the 4 chunks)
    if (slot == 0) {
        uint4 su = q4[(size_t)v * 4 + c];
        float ssc = qs[v];
        const uint32 wd[4] = {su.x, su.y, su.z, su.w};
#pragma unroll
        for (int wi = 0; wi < 4; ++wi) {
            acc[wi * 4 + 0] = ssc * sb0(wd[wi]);
            acc[wi * 4 + 1] = ssc * sb1(wd[wi]);
            acc[wi * 4 + 2] = ssc * sb2(wd[wi]);
            acc[wi * 4 + 3] = ssc * sb3(wd[wi]);
        }
    }

    for (int base = rs; base < re; base += 64) {
        int ed  = elist[min(base + L, re - 1)];  // 64 edges, one per lane
        float qv = qs[ed];                       // matching scales
#pragma unroll 1
        for (int half = 0; half < 2; ++half) {   // 32-edge windows
            if (half == 1 && base + 32 >= re) break;
#pragma unroll
            for (int t = half * 2; t < half * 2 + 2; ++t) {  // 2 gathers/window
                int e = t * 16 + slot;
                int s = __shfl(ed, e);
                float sc = __shfl(qv, e);
                sc = (base + e < re) ? sc : 0.f;
                uint4 u = q4[(size_t)s * 4 + c];
                const uint32 wd[4] = {u.x, u.y, u.z, u.w};
#pragma unroll
                for (int wi = 0; wi < 4; ++wi) {
                    acc[wi * 4 + 0] = fmaf(sc, sb0(wd[wi]), acc[wi * 4 + 0]);
                    acc[wi * 4 + 1] = fmaf(sc, sb1(wd[wi]), acc[wi * 4 + 1]);
                    acc[wi * 4 + 2] = fmaf(sc, sb2(wd[wi]), acc[wi * 4 + 2]);
                    acc[wi * 4 + 3] = fmaf(sc, sb3(wd[wi]), acc[wi * 4 + 3]);
                }
            }
        }
    }

    // reduce 16 edge slots (lane bits 2..5)
#pragma unroll
    for (int i = 0; i < 16; ++i) {
        acc[i] += __shfl_xor(acc[i], 4);
        acc[i] += __shfl_xor(acc[i], 8);
        acc[i] += __shfl_xor(acc[i], 16);
        acc[i] += __shfl_xor(acc[i], 32);
    }

    if (slot == 0) {
        float b[16];
#pragma unroll
        for (int i = 0; i < 16; ++i) b[i] = 0.f;
        if constexpr (BIAS) {
#pragma unroll
            for (int wi = 0; wi < 4; ++wi) {
                float4 bv = ((const float4*)bias)[c * 4 + wi];
                b[wi * 4 + 0] = bv.x; b[wi * 4 + 1] = bv.y;
                b[wi * 4 + 2] = bv.z; b[wi * 4 + 3] = bv.w;
            }
        }
        float o[16];
#pragma unroll
        for (int i = 0; i < 16; ++i) o[i] = fmaf(dv, acc[i], b[i]);
        bool f32out = false;
        if constexpr (OUT_NATIVE) f32out = (*flag == 0);
        if (f32out) {
#pragma unroll
            for (int wi = 0; wi < 4; ++wi)
                ((float4*)outv)[(size_t)v * 16 + c * 4 + wi] =
                    make_float4(o[wi * 4 + 0], o[wi * 4 + 1],
                                o[wi * 4 + 2], o[wi * 4 + 3]);
        } else {
            ((uint4*)outv)[(size_t)v * 8 + c * 2 + 0] =
                make_uint4(pack_bf(o[0], o[1]), pack_bf(o[2], o[3]),
                           pack_bf(o[4], o[5]), pack_bf(o[6], o[7]));
            ((uint4*)outv)[(size_t)v * 8 + c * 2 + 1] =
                make_uint4(pack_bf(o[8], o[9]), pack_bf(o[10], o[11]),
                           pack_bf(o[12], o[13]), pack_bf(o[14], o[15]));
        }
    }
}

// ---------------- BN stats over bf16 [n,C] buffer ----------------
// uint2 per lane (4 channels); 256 blocks (small atomic fan-in).

template <int C2>
__global__ __launch_bounds__(256) void stat_k(const uint2* __restrict__ buf,
                                              float* __restrict__ stats, int n) {
    constexpr int LPR = C2 / 2;      // lanes per row
    constexpr int RPB = 256 / LPR;   // rows per block-iteration
    constexpr int C = 2 * C2;
    const int lp = threadIdx.x % LPR;
    const int rg = threadIdx.x / LPR;
    float s0 = 0.f, s1 = 0.f, s2 = 0.f, s3 = 0.f;
    float q0 = 0.f, q1 = 0.f, q2 = 0.f, q3 = 0.f;
    for (int r = blockIdx.x * RPB + rg; r < n; r += gridDim.x * RPB) {
        uint2 u = buf[(size_t)r * LPR + lp];
        float f0 = bf_lo(u.x), f1 = bf_hi(u.x);
        float f2 = bf_lo(u.y), f3 = bf_hi(u.y);
        s0 += f0; q0 = fmaf(f0, f0, q0);
        s1 += f1; q1 = fmaf(f1, f1, q1);
        s2 += f2; q2 = fmaf(f2, f2, q2);
        s3 += f3; q3 = fmaf(f3, f3, q3);
    }
    __shared__ float sd[2 * C];
    for (int i = threadIdx.x; i < 2 * C; i += 256) sd[i] = 0.f;
    __syncthreads();
    atomicAdd(&sd[4 * lp + 0], s0);
    atomicAdd(&sd[4 * lp + 1], s1);
    atomicAdd(&sd[4 * lp + 2], s2);
    atomicAdd(&sd[4 * lp + 3], s3);
    atomicAdd(&sd[C + 4 * lp + 0], q0);
    atomicAdd(&sd[C + 4 * lp + 1], q1);
    atomicAdd(&sd[C + 4 * lp + 2], q2);
    atomicAdd(&sd[C + 4 * lp + 3], q3);
    __syncthreads();
    for (int i = threadIdx.x; i < 2 * C; i += 256) atomicAdd(&stats[i], sd[i]);
}

// ---------------- GEMM: out = epilogue( act(A) @ W ) ----------------
// A [n,K] bf16 flat, W [K,N] f32. XOR-swizzled Ast staging.
// AFFS: in-block BN coefs from raw stats. BIAS: +bias[col]. DINV: row scale.
// QUANT (requires N=64, CG=16, DINV): int8 per-row output via 16-lane
// shfl-max (row spans lanes tc=0..15 of one wave subgroup) -> q + qs.

template <int K, int N, int MR, bool AFFS, bool BIAS, bool DINV, bool QUANT>
__global__ __launch_bounds__(256) void gemm_k(
    const __hip_bfloat16* __restrict__ A, const float* __restrict__ W,
    const float* __restrict__ stats, const float* __restrict__ g,
    const float* __restrict__ be, float invN,
    const float* __restrict__ bias, const float* __restrict__ dinv,
    __hip_bfloat16* __restrict__ out, uint32* __restrict__ qout,
    float* __restrict__ qscale, int n) {
    constexpr int CG = N / 4;        // threads across columns
    constexpr int RG = 256 / CG;     // row groups
    constexpr int TM = RG * MR;      // rows per block
    __shared__ __align__(16) float Ws[K * N];
    __shared__ __align__(16) float Ast[K * TM];
    __shared__ float cf[AFFS ? 2 * K : 1];

    const int tid = threadIdx.x;
    if constexpr (AFFS) {
        if (tid < K) {
            float mean = stats[tid] * invN;
            float var  = fmaxf(fmaf(-mean, mean, stats[K + tid] * invN), 0.f);
            float a    = g[tid] * rsqrtf(var + EPS_BN);
            cf[tid]     = a;
            cf[K + tid] = be[tid] - mean * a;
        }
        __syncthreads();
    }

    for (int i = tid; i < K * N / 4; i += 256)
        ((float4*)Ws)[i] = ((const float4*)W)[i];

    const int row0 = blockIdx.x * TM;
    constexpr int KC = K / 4;
    for (int i = tid; i < TM * KC; i += 256) {
        int r  = i / KC;
        int c4 = (i - r * KC) * 4;
        int gr = row0 + r;
        float f0 = 0.f, f1 = 0.f, f2 = 0.f, f3 = 0.f;
        if (gr < n) {
            uint2 u = *(const uint2*)(A + (size_t)gr * K + c4);
            f0 = bf_lo(u.x); f1 = bf_hi(u.x);
            f2 = bf_lo(u.y); f3 = bf_hi(u.y);
            if constexpr (AFFS) {
                f0 = fmaf(cf[c4 + 0], f0, cf[K + c4 + 0]); f0 = f0 > 0.f ? f0 : LEAKY * f0;
                f1 = fmaf(cf[c4 + 1], f1, cf[K + c4 + 1]); f1 = f1 > 0.f ? f1 : LEAKY * f1;
                f2 = fmaf(cf[c4 + 2], f2, cf[K + c4 + 2]); f2 = f2 > 0.f ? f2 : LEAKY * f2;
                f3 = fmaf(cf[c4 + 3], f3, cf[K + c4 + 3]); f3 = f3 > 0.f ? f3 : LEAKY * f3;
            }
        }
        const int rr = r ^ (4 * ((c4 >> 2) & 7));
        Ast[(c4 + 0) * TM + rr] = f0;
        Ast[(c4 + 1) * TM + rr] = f1;
        Ast[(c4 + 2) * TM + rr] = f2;
        Ast[(c4 + 3) * TM + rr] = f3;
    }
    __syncthreads();

    const int tr = tid / CG, tc = tid % CG;
    float acc[MR][4];
#pragma unroll
    for (int m = 0; m < MR; ++m)
#pragma unroll
        for (int j = 0; j < 4; ++j) acc[m][j] = 0.f;

#pragma unroll 4
    for (int k = 0; k < K; ++k) {
        float4 w = *(const float4*)&Ws[k * N + tc * 4];
        const int sk = 4 * ((k >> 2) & 7);
        float am[MR];
        if constexpr (MR == 4) {
            float4 t = *(const float4*)&Ast[k * TM + ((tr * 4) ^ sk)];
            am[0] = t.x; am[1] = t.y; am[2] = t.z; am[3] = t.w;
        } else {
            float2 t = *(const float2*)&Ast[k * TM + ((tr * 2) ^ sk)];
            am[0] = t.x; am[1] = t.y;
        }
#pragma unroll
        for (int m = 0; m < MR; ++m) {
            acc[m][0] = fmaf(am[m], w.x, acc[m][0]);
            acc[m][1] = fmaf(am[m], w.y, acc[m][1]);
            acc[m][2] = fmaf(am[m], w.z, acc[m][2]);
            acc[m][3] = fmaf(am[m], w.w, acc[m][3]);
        }
    }

    float bv[4] = {0.f, 0.f, 0.f, 0.f};
    if constexpr (BIAS) {
#pragma unroll
        for (int j = 0; j < 4; ++j) bv[j] = bias[tc * 4 + j];
    }

#pragma unroll
    for (int m = 0; m < MR; ++m) {
        int gr = row0 + tr * MR + m;
        float sc = 1.f;
        if constexpr (DINV) sc = (gr < n) ? dinv[gr] : 0.f;
        float val[4];
#pragma unroll
        for (int j = 0; j < 4; ++j) {
            float v = acc[m][j];
            if constexpr (BIAS) v += bv[j];
            else                v *= sc;
            val[j] = v;
        }
        if constexpr (QUANT) {
            // row gr spans lanes tc=0..15 of this 16-lane subgroup
            float rm = fmaxf(fmaxf(fabsf(val[0]), fabsf(val[1])),
                             fmaxf(fabsf(val[2]), fabsf(val[3])));
            rm = fmaxf(rm, __shfl_xor(rm, 1));
            rm = fmaxf(rm, __shfl_xor(rm, 2));
            rm = fmaxf(rm, __shfl_xor(rm, 4));
            rm = fmaxf(rm, __shfl_xor(rm, 8));
            float inv = (rm > 0.f) ? 127.0f / rm : 0.f;
            if (gr < n) {
                int b0 = (int)rintf(val[0] * inv);
                int b1 = (int)rintf(val[1] * inv);
                int b2 = (int)rintf(val[2] * inv);
                int b3 = (int)rintf(val[3] * inv);
                qout[(size_t)gr * 16 + tc] =
                    (uint32)(b0 & 0xFF) | ((uint32)(b1 & 0xFF) << 8) |
                    ((uint32)(b2 & 0xFF) << 16) | ((uint32)(b3 & 0xFF) << 24);
                if (tc == 0) qscale[gr] = rm * (1.0f / 127.0f);
            }
        } else {
            if (gr < n) {
                __attribute__((aligned(8))) __hip_bfloat16 pk[4];
#pragma unroll
                for (int j = 0; j < 4; ++j) pk[j] = __float2bfloat16(val[j]);
                *(uint2*)(out + (size_t)gr * N + tc * 4) = *(const uint2*)pk;
            }
        }
    }
}

// ---------------- host ----------------

extern "C" void kernel_launch(void* const* d_in, const int* in_sizes, int n_in,
                              void* d_out, int out_size, void* d_ws, size_t ws_size,
                              hipStream_t stream) {
    const int n = in_sizes[0] / 64;   // 50000
    const int E = in_sizes[1] / 2;    // 800000

    const void* x  = d_in[0];
    const int*  ei = (const int*)d_in[1];

    // workspace carve (256B aligned) — total ~30 MB
    char* w = (char*)d_ws;
    auto alloc = [&](size_t bytes) -> void* {
        void* p = (void*)w;
        w += (bytes + 255) & ~(size_t)255;
        return p;
    };
    int*   flag      = (int*)alloc(256);
    float* Wf        = (float*)alloc(21120 * 4);            // converted params
    int*   pbc       = (int*)alloc((size_t)CB * NBIN * 4);
    int*   bb        = (int*)alloc((NBIN + 2) * 4);
    int*   row_start = (int*)alloc((size_t)(n + 1) * 4);
    int*   elist     = (int*)alloc((size_t)E * 4);
    uint32* ebuf     = (uint32*)alloc((size_t)E * 4);       // packed (src<<8)|dl
    float* dinv      = (float*)alloc((size_t)n * 4);
    float* stats1    = (float*)alloc(256 * 4);
    float* stats2    = (float*)alloc(128 * 4);
    uint32* q        = (uint32*)alloc((size_t)n * 16 * 4);  // int8 rows (xs/hd2/hd3)
    float*  qsA      = (float*)alloc((size_t)n * 4);        // per-row scales
    __hip_bfloat16* B1 = (__hip_bfloat16*)alloc((size_t)n * 64 * 2);   // AX (bf16)
    __hip_bfloat16* B2 = (__hip_bfloat16*)alloc((size_t)n * 128 * 2);  // out1 / out2

    // param offsets inside Wf
    float* W1f = Wf + 0;     float* b1f = Wf + 8192;
    float* g1f = Wf + 8320;  float* be1f = Wf + 8448;
    float* W2f = Wf + 8576;  float* b2f = Wf + 16768;
    float* g2f = Wf + 16832; float* be2f = Wf + 16896;
    float* W3f = Wf + 16960; float* b3f = Wf + 21056;

    const float invN = 1.0f / (float)n;
    const int nbins = (n + 255) >> 8;        // bins of 256 nodes
    const int ab    = (n + 3) / 4;           // one wave per node, 4 waves/block

    // 1: detect + cvt params + zero stats + bin count (merged, independent)
    setup_cnt_k<<<212, 256, 0, stream>>>((const uint32*)x, flag,
        d_in[2], d_in[3], d_in[4], d_in[5], d_in[6], d_in[7], d_in[8], d_in[9],
        d_in[10], d_in[11], Wf, stats1, stats2, ei + E, pbc, E);
    // 2-4: atomic-free radix CSR build + int8 xs (dinv-folded scales)
    scan2_k<<<1, 256, 0, stream>>>(pbc, bb, row_start + n, E);
    scat_k<<<CB, 256, 0, stream>>>(ei, ei + E, pbc, ebuf, E);
    fill2_k<<<nbins, 256, 0, stream>>>(ebuf, bb, row_start, elist, x, flag,
                                       q, qsA, dinv, n);

    // Layer 1 (aggregate-first): B1 = A_hat x ; out1(B2) = B1@W1 + b1 ; stats1
    agg_k<false, false><<<ab, 256, 0, stream>>>(q, qsA, dinv, row_start, elist,
                                                nullptr, B1, flag, n);
    gemm_k<64, 128, 4, false, true, false, false><<<(n + 31) / 32, 256, 0, stream>>>(
        B1, W1f, nullptr, nullptr, nullptr, 0.f, b1f, nullptr, B2, nullptr, nullptr, n);
    stat_k<64><<<256, 256, 0, stream>>>((const uint2*)B2, stats1, n);

    // Layer 2: q = int8( (BN+leaky(out1)@W2)*dinv ) ; out2(B2) = gather + b2 ; stats2
    gemm_k<128, 64, 4, true, false, true, true><<<(n + 63) / 64, 256, 0, stream>>>(
        B2, W2f, stats1, g1f, be1f, invN, nullptr, dinv, nullptr, q, qsA, n);
    agg_k<true, false><<<ab, 256, 0, stream>>>(q, qsA, dinv, row_start, elist,
                                               b2f, B2, flag, n);
    stat_k<32><<<256, 256, 0, stream>>>((const uint2*)B2, stats2, n);

    // Layer 3: q = int8( (BN+leaky(out2)@W3)*dinv ) ; out = gather + b3 (native)
    gemm_k<64, 64, 4, true, false, true, true><<<(n + 63) / 64, 256, 0, stream>>>(
        B2, W3f, stats2, g2f, be2f, invN, nullptr, dinv, nullptr, q, qsA, n);
    agg_k<true, true><<<ab, 256, 0, stream>>>(q, qsA, dinv, row_start, elist,
                                              b3f, d_out, flag, n);
}

// Round 9
// 284.452 us; speedup vs baseline: 4.4223x; 1.1850x over previous
//
#include <hip/hip_runtime.h>
#include <hip/hip_bf16.h>

// ---------------------------------------------------------------------------
// GCNEncoder: 3x (GCNConv -> [BN -> LeakyReLU]), N=50000 nodes, E=800000 edges.
//   Layer1 aggregate-first:  out1 = (A_hat X) W1 + b1
//   Layers2/3 transform-first: hd = (act(prev) @ W) * dinv; out = gather + bias
// R23 = R17 loop structure, but messages switch int8+scale -> bf16 rows
// PRE-SCALED by dinv[src]:
//   - xs[v] = x[v]*dinv[v] (bf16, fill2); hd = (act@W)*dinv (gemm DINV path).
//   - agg gathers 128B bf16 rows; NO qs gather (was ~60 wasted lines + one
//     full latency round per 64-edge batch), shfl count halved, no scale mul.
//   - gemm2/3 lose the QUANT epilogue; fill2 loses the quant block.
//   - accuracy improves (bf16 messages vs int8-per-row).
// Kept: R17 agg loop (16-edge batch, 4 gathers in flight, early break),
// radix CSR, merged setup+cnt, separate stat_k.
// ---------------------------------------------------------------------------

#define LEAKY 0.01f
#define EPS_BN 1e-5f
#define NBIN 256
#define CB   128

typedef unsigned int uint32;

static __device__ __forceinline__ float bf_lo(uint32 u) { return __uint_as_float(u << 16); }
static __device__ __forceinline__ float bf_hi(uint32 u) { return __uint_as_float(u & 0xFFFF0000u); }

static __device__ __forceinline__ uint32 pack_bf(float x, float y) {
    __hip_bfloat16 bx = __float2bfloat16(x), by = __float2bfloat16(y);
    return (uint32)(*(unsigned short*)&bx) | ((uint32)(*(unsigned short*)&by) << 16);
}

// ---- merged: dtype detect + param convert (b<83) | zero stats (b==83) |
// ----         radix bin count (84..211)  -- all independent work ----------

__global__ __launch_bounds__(256) void setup_cnt_k(
    const uint32* __restrict__ x, int* __restrict__ flag,
    const void* p0, const void* p1, const void* p2, const void* p3,
    const void* p4, const void* p5, const void* p6, const void* p7,
    const void* p8, const void* p9, float* __restrict__ dst,
    float* __restrict__ stats1, float* __restrict__ stats2,
    const int* __restrict__ dstE, int* __restrict__ pbc, int E) {
    const int b = blockIdx.x, t = threadIdx.x;
    if (b < 83) {
        __shared__ int sd[256];
        int c = 0;
        for (int j = 0; j < 16; ++j) {
            uint32 w = x[t * 16 + j];
            uint32 m = w & 0x7FFFu;
            uint32 e = (w >> 7) & 0xFFu;
            if (m == 0u || (e >= 100u && e <= 150u)) ++c;
        }
        sd[t] = c;
        __syncthreads();
        for (int off = 128; off > 0; off >>= 1) {
            if (t < off) sd[t] += sd[t + off];
            __syncthreads();
        }
        bool bf = (sd[0] >= 3072);
        if (b == 0 && t == 0) *flag = bf ? 1 : 0;
        int i = b * 256 + t;
        if (i < 21120) {
            const void* p;
            int j;
            if      (i <  8192) { p = p0; j = i;         }
            else if (i <  8320) { p = p1; j = i - 8192;  }
            else if (i <  8448) { p = p2; j = i - 8320;  }
            else if (i <  8576) { p = p3; j = i - 8448;  }
            else if (i < 16768) { p = p4; j = i - 8576;  }
            else if (i < 16832) { p = p5; j = i - 16768; }
            else if (i < 16896) { p = p6; j = i - 16832; }
            else if (i < 16960) { p = p7; j = i - 16896; }
            else if (i < 21056) { p = p8; j = i - 16960; }
            else                { p = p9; j = i - 21056; }
            dst[i] = bf ? __bfloat162float(((const __hip_bfloat16*)p)[j])
                        : ((const float*)p)[j];
        }
    } else if (b == 83) {
        stats1[t] = 0.f;
        if (t < 128) stats2[t] = 0.f;
    } else {
        __shared__ int c[NBIN];
        c[t] = 0;
        __syncthreads();
        const int cb = b - 84;
        const int chunk = (E + CB - 1) / CB;
        const int lo = cb * chunk, hi = min(E, lo + chunk);
        for (int i = lo + t; i < hi; i += 256)
            atomicAdd(&c[dstE[i] >> 8], 1);
        __syncthreads();
        pbc[t * CB + cb] = c[t];
    }
}

// one block, 256 threads (thread j owns bin j); prefix over CB in registers.
__global__ __launch_bounds__(256) void scan2_k(int* __restrict__ pbc,
                                               int* __restrict__ bb,
                                               int* __restrict__ row_end, int E) {
    const int j = threadIdx.x;
    int4 vals[CB / 4];
    int tot = 0;
#pragma unroll
    for (int c = 0; c < CB / 4; ++c) {
        vals[c] = ((const int4*)(pbc + j * CB))[c];
        tot += vals[c].x + vals[c].y + vals[c].z + vals[c].w;
    }
    __shared__ int sd[NBIN];
    sd[j] = tot;
    __syncthreads();
    for (int off = 1; off < NBIN; off <<= 1) {
        int x = (j >= off) ? sd[j - off] : 0;
        __syncthreads();
        sd[j] += x;
        __syncthreads();
    }
    int run = sd[j] - tot;   // exclusive bucket base
    bb[j] = run;
    if (j == 0) *row_end = E;
#pragma unroll
    for (int c = 0; c < CB / 4; ++c) {
        int4 v = vals[c];
        int a0 = run; run += v.x;
        int a1 = run; run += v.y;
        int a2 = run; run += v.z;
        int a3 = run; run += v.w;
        ((int4*)(pbc + j * CB))[c] = make_int4(a0, a1, a2, a3);
    }
}

// packed edge record: (src << 8) | (dst & 255). bin implied by position.
__global__ __launch_bounds__(256) void scat_k(const int* __restrict__ src,
                                              const int* __restrict__ dst,
                                              const int* __restrict__ pbc,
                                              uint32* __restrict__ ebuf, int E) {
    __shared__ int cur[NBIN];
    cur[threadIdx.x] = pbc[threadIdx.x * CB + blockIdx.x];
    __syncthreads();
    const int chunk = (E + CB - 1) / CB;
    const int lo = blockIdx.x * chunk, hi = min(E, lo + chunk);
    for (int i = lo + threadIdx.x; i < hi; i += 256) {
        int d = dst[i];
        int p = atomicAdd(&cur[d >> 8], 1);      // LDS atomic
        ebuf[p] = ((uint32)src[i] << 8) | (uint32)(d & 255);
    }
}

// one block per bin (256 nodes): CSR rows + elist (src ids, L2-local window) +
// xs[v] = x[v]*dinv[v] as bf16 (pre-scaled messages) + dinv.
__global__ __launch_bounds__(256) void fill2_k(
    const uint32* __restrict__ ebuf, const int* __restrict__ bb,
    int* __restrict__ row_start, int* __restrict__ elist,
    const void* __restrict__ xv, const int* __restrict__ flag,
    uint2* __restrict__ xs, float* __restrict__ dinv, int n) {
    __shared__ int cntl[NBIN], curl[NBIN], sd[NBIN];
    const int j = blockIdx.x, t = threadIdx.x;
    const int lo = j << 8;
    const int hi = min(n, lo + 256);
    const int nn = hi - lo;
    if (nn <= 0) return;
    const int eb = bb[j], ee = bb[j + 1];

    cntl[t] = 0;
    __syncthreads();
    for (int i = eb + t; i < ee; i += 256)
        atomicAdd(&cntl[ebuf[i] & 255u], 1);     // LDS atomic
    __syncthreads();
    int cv = cntl[t];
    sd[t] = cv;
    __syncthreads();
    for (int off = 1; off < NBIN; off <<= 1) {
        int x = (t >= off) ? sd[t - off] : 0;
        __syncthreads();
        sd[t] += x;
        __syncthreads();
    }
    int pref = sd[t] - cv;                        // exclusive
    if (t < nn) row_start[lo + t] = eb + pref;
    curl[t] = pref;
    __syncthreads();
    for (int i = eb + t; i < ee; i += 256) {
        uint32 e = ebuf[i];
        int p = atomicAdd(&curl[e & 255u], 1);    // LDS atomic
        elist[eb + p] = (int)(e >> 8);
    }
    // per-thread node row: xs = x * dinv, bf16
    const int v = lo + t;
    if (v < hi) {
        const bool bf = (*flag != 0);
        float d = rsqrtf((float)(cntl[t] + 1));
        dinv[v] = d;
        if (bf) {
#pragma unroll
            for (int c = 0; c < 16; ++c) {
                uint2 u = ((const uint2*)xv)[(size_t)v * 16 + c];
                float f0 = bf_lo(u.x) * d, f1 = bf_hi(u.x) * d;
                float f2 = bf_lo(u.y) * d, f3 = bf_hi(u.y) * d;
                xs[(size_t)v * 16 + c] = make_uint2(pack_bf(f0, f1), pack_bf(f2, f3));
            }
        } else {
#pragma unroll
            for (int c = 0; c < 16; ++c) {
                float4 f = ((const float4*)xv)[(size_t)v * 16 + c];
                xs[(size_t)v * 16 + c] =
                    make_uint2(pack_bf(f.x * d, f.y * d), pack_bf(f.z * d, f.w * d));
            }
        }
    }
}

// ---------------- aggregation: bf16 pre-scaled rows, one wave/node ---------
// B: [n][16] uint2 rows (64ch bf16, already *dinv[src]). Lane j=L&15 covers
// 4 ch (8B), r=L>>4 edge slot -> 4 edges per gather instr, 16-edge batches
// with early break, 4 gathers in flight (R17 structure). NO per-edge scale:
// only the src id is shfl'd; OOB slots masked by m=0. Fold xor(16|32).
// out = dinv[v]*acc + bias.

template <bool BIAS, bool OUT_NATIVE>
__global__ __launch_bounds__(256) void agg_k(
    const uint2* __restrict__ B, const float* __restrict__ dinv,
    const int* __restrict__ row_start, const int* __restrict__ elist,
    const float* __restrict__ bias, void* __restrict__ outv,
    const int* __restrict__ flag, int n) {
    const int v = blockIdx.x * 4 + (threadIdx.x >> 6);
    if (v >= n) return;
    const int L = threadIdx.x & 63;
    const int r = L >> 4;      // edge slot 0..3
    const int j = L & 15;      // uint2 (4ch) within 128B row

    const int rs = row_start[v], re = row_start[v + 1];
    const float dv = dinv[v];

    uint2 su = B[(size_t)v * 16 + j];
    float a0 = 0.f, a1 = 0.f, a2 = 0.f, a3 = 0.f;
    if (r == 0) {              // self-loop (row already has dinv folded)
        a0 = bf_lo(su.x); a1 = bf_hi(su.x);
        a2 = bf_lo(su.y); a3 = bf_hi(su.y);
    }

    for (int base = rs; base < re; base += 64) {
        int ed = elist[min(base + L, re - 1)];   // 64 edges, one per lane
#pragma unroll 1
        for (int k = 0; k < 4; ++k) {            // wave-uniform 16-edge batches
            if (base + k * 16 >= re) break;
#pragma unroll
            for (int t = 0; t < 4; ++t) {        // 4 gathers in flight
                int e = k * 16 + t * 4 + r;
                int s = __shfl(ed, e);
                float m = (base + e < re) ? 1.f : 0.f;
                uint2 u = B[(size_t)s * 16 + j];
                a0 = fmaf(m, bf_lo(u.x), a0);
                a1 = fmaf(m, bf_hi(u.x), a1);
                a2 = fmaf(m, bf_lo(u.y), a2);
                a3 = fmaf(m, bf_hi(u.y), a3);
            }
        }
    }

    a0 += __shfl_xor(a0, 16); a1 += __shfl_xor(a1, 16);
    a2 += __shfl_xor(a2, 16); a3 += __shfl_xor(a3, 16);
    a0 += __shfl_xor(a0, 32); a1 += __shfl_xor(a1, 32);
    a2 += __shfl_xor(a2, 32); a3 += __shfl_xor(a3, 32);

    if (L < 16) {
        float b0 = 0.f, b1 = 0.f, b2 = 0.f, b3 = 0.f;
        if constexpr (BIAS) {
            float4 bv = ((const float4*)bias)[j];
            b0 = bv.x; b1 = bv.y; b2 = bv.z; b3 = bv.w;
        }
        float v0 = fmaf(dv, a0, b0), v1 = fmaf(dv, a1, b1);
        float v2 = fmaf(dv, a2, b2), v3 = fmaf(dv, a3, b3);
        if constexpr (OUT_NATIVE) {
            if (*flag != 0) {
                ((uint2*)outv)[(size_t)v * 16 + j] =
                    make_uint2(pack_bf(v0, v1), pack_bf(v2, v3));
            } else {
                ((float4*)outv)[(size_t)v * 16 + j] = make_float4(v0, v1, v2, v3);
            }
        } else {
            ((uint2*)outv)[(size_t)v * 16 + j] =
                make_uint2(pack_bf(v0, v1), pack_bf(v2, v3));
        }
    }
}

// ---------------- BN stats over bf16 [n,C] buffer ----------------
// uint2 per lane (4 channels); 256 blocks (small atomic fan-in).

template <int C2>
__global__ __launch_bounds__(256) void stat_k(const uint2* __restrict__ buf,
                                              float* __restrict__ stats, int n) {
    constexpr int LPR = C2 / 2;      // lanes per row
    constexpr int RPB = 256 / LPR;   // rows per block-iteration
    constexpr int C = 2 * C2;
    const int lp = threadIdx.x % LPR;
    const int rg = threadIdx.x / LPR;
    float s0 = 0.f, s1 = 0.f, s2 = 0.f, s3 = 0.f;
    float q0 = 0.f, q1 = 0.f, q2 = 0.f, q3 = 0.f;
    for (int r = blockIdx.x * RPB + rg; r < n; r += gridDim.x * RPB) {
        uint2 u = buf[(size_t)r * LPR + lp];
        float f0 = bf_lo(u.x), f1 = bf_hi(u.x);
        float f2 = bf_lo(u.y), f3 = bf_hi(u.y);
        s0 += f0; q0 = fmaf(f0, f0, q0);
        s1 += f1; q1 = fmaf(f1, f1, q1);
        s2 += f2; q2 = fmaf(f2, f2, q2);
        s3 += f3; q3 = fmaf(f3, f3, q3);
    }
    __shared__ float sd[2 * C];
    for (int i = threadIdx.x; i < 2 * C; i += 256) sd[i] = 0.f;
    __syncthreads();
    atomicAdd(&sd[4 * lp + 0], s0);
    atomicAdd(&sd[4 * lp + 1], s1);
    atomicAdd(&sd[4 * lp + 2], s2);
    atomicAdd(&sd[4 * lp + 3], s3);
    atomicAdd(&sd[C + 4 * lp + 0], q0);
    atomicAdd(&sd[C + 4 * lp + 1], q1);
    atomicAdd(&sd[C + 4 * lp + 2], q2);
    atomicAdd(&sd[C + 4 * lp + 3], q3);
    __syncthreads();
    for (int i = threadIdx.x; i < 2 * C; i += 256) atomicAdd(&stats[i], sd[i]);
}

// ---------------- GEMM: out = epilogue( act(A) @ W ) ----------------
// A [n,K] bf16 flat, W [K,N] f32. XOR-swizzled Ast staging.
// AFFS: in-block BN coefs from raw stats. BIAS: +bias[col]. DINV: row scale
// (pre-folds dinv into the bf16 output rows for the next aggregation).

template <int K, int N, int MR, bool AFFS, bool BIAS, bool DINV>
__global__ __launch_bounds__(256) void gemm_k(
    const __hip_bfloat16* __restrict__ A, const float* __restrict__ W,
    const float* __restrict__ stats, const float* __restrict__ g,
    const float* __restrict__ be, float invN,
    const float* __restrict__ bias, const float* __restrict__ dinv,
    __hip_bfloat16* __restrict__ out, int n) {
    constexpr int CG = N / 4;        // threads across columns
    constexpr int RG = 256 / CG;     // row groups
    constexpr int TM = RG * MR;      // rows per block
    __shared__ __align__(16) float Ws[K * N];
    __shared__ __align__(16) float Ast[K * TM];
    __shared__ float cf[AFFS ? 2 * K : 1];

    const int tid = threadIdx.x;
    if constexpr (AFFS) {
        if (tid < K) {
            float mean = stats[tid] * invN;
            float var  = fmaxf(fmaf(-mean, mean, stats[K + tid] * invN), 0.f);
            float a    = g[tid] * rsqrtf(var + EPS_BN);
            cf[tid]     = a;
            cf[K + tid] = be[tid] - mean * a;
        }
        __syncthreads();
    }

    for (int i = tid; i < K * N / 4; i += 256)
        ((float4*)Ws)[i] = ((const float4*)W)[i];

    const int row0 = blockIdx.x * TM;
    constexpr int KC = K / 4;
    for (int i = tid; i < TM * KC; i += 256) {
        int r  = i / KC;
        int c4 = (i - r * KC) * 4;
        int gr = row0 + r;
        float f0 = 0.f, f1 = 0.f, f2 = 0.f, f3 = 0.f;
        if (gr < n) {
            uint2 u = *(const uint2*)(A + (size_t)gr * K + c4);
            f0 = bf_lo(u.x); f1 = bf_hi(u.x);
            f2 = bf_lo(u.y); f3 = bf_hi(u.y);
            if constexpr (AFFS) {
                f0 = fmaf(cf[c4 + 0], f0, cf[K + c4 + 0]); f0 = f0 > 0.f ? f0 : LEAKY * f0;
                f1 = fmaf(cf[c4 + 1], f1, cf[K + c4 + 1]); f1 = f1 > 0.f ? f1 : LEAKY * f1;
                f2 = fmaf(cf[c4 + 2], f2, cf[K + c4 + 2]); f2 = f2 > 0.f ? f2 : LEAKY * f2;
                f3 = fmaf(cf[c4 + 3], f3, cf[K + c4 + 3]); f3 = f3 > 0.f ? f3 : LEAKY * f3;
            }
        }
        const int rr = r ^ (4 * ((c4 >> 2) & 7));
        Ast[(c4 + 0) * TM + rr] = f0;
        Ast[(c4 + 1) * TM + rr] = f1;
        Ast[(c4 + 2) * TM + rr] = f2;
        Ast[(c4 + 3) * TM + rr] = f3;
    }
    __syncthreads();

    const int tr = tid / CG, tc = tid % CG;
    float acc[MR][4];
#pragma unroll
    for (int m = 0; m < MR; ++m)
#pragma unroll
        for (int j = 0; j < 4; ++j) acc[m][j] = 0.f;

#pragma unroll 4
    for (int k = 0; k < K; ++k) {
        float4 w = *(const float4*)&Ws[k * N + tc * 4];
        const int sk = 4 * ((k >> 2) & 7);
        float am[MR];
        if constexpr (MR == 4) {
            float4 t = *(const float4*)&Ast[k * TM + ((tr * 4) ^ sk)];
            am[0] = t.x; am[1] = t.y; am[2] = t.z; am[3] = t.w;
        } else {
            float2 t = *(const float2*)&Ast[k * TM + ((tr * 2) ^ sk)];
            am[0] = t.x; am[1] = t.y;
        }
#pragma unroll
        for (int m = 0; m < MR; ++m) {
            acc[m][0] = fmaf(am[m], w.x, acc[m][0]);
            acc[m][1] = fmaf(am[m], w.y, acc[m][1]);
            acc[m][2] = fmaf(am[m], w.z, acc[m][2]);
            acc[m][3] = fmaf(am[m], w.w, acc[m][3]);
        }
    }

    float bv[4] = {0.f, 0.f, 0.f, 0.f};
    if constexpr (BIAS) {
#pragma unroll
        for (int j = 0; j < 4; ++j) bv[j] = bias[tc * 4 + j];
    }

#pragma unroll
    for (int m = 0; m < MR; ++m) {
        int gr = row0 + tr * MR + m;
        float sc = 1.f;
        if constexpr (DINV) sc = (gr < n) ? dinv[gr] : 0.f;
        float val[4];
#pragma unroll
        for (int j = 0; j < 4; ++j) {
            float v = acc[m][j];
            if constexpr (BIAS) v += bv[j];
            else                v *= sc;
            val[j] = v;
        }
        if (gr < n) {
            __attribute__((aligned(8))) __hip_bfloat16 pk[4];
#pragma unroll
            for (int j = 0; j < 4; ++j) pk[j] = __float2bfloat16(val[j]);
            *(uint2*)(out + (size_t)gr * N + tc * 4) = *(const uint2*)pk;
        }
    }
}

// ---------------- host ----------------

extern "C" void kernel_launch(void* const* d_in, const int* in_sizes, int n_in,
                              void* d_out, int out_size, void* d_ws, size_t ws_size,
                              hipStream_t stream) {
    const int n = in_sizes[0] / 64;   // 50000
    const int E = in_sizes[1] / 2;    // 800000

    const void* x  = d_in[0];
    const int*  ei = (const int*)d_in[1];

    // workspace carve (256B aligned)
    char* w = (char*)d_ws;
    auto alloc = [&](size_t bytes) -> void* {
        void* p = (void*)w;
        w += (bytes + 255) & ~(size_t)255;
        return p;
    };
    int*   flag      = (int*)alloc(256);
    float* Wf        = (float*)alloc(21120 * 4);            // converted params
    int*   pbc       = (int*)alloc((size_t)CB * NBIN * 4);
    int*   bb        = (int*)alloc((NBIN + 2) * 4);
    int*   row_start = (int*)alloc((size_t)(n + 1) * 4);
    int*   elist     = (int*)alloc((size_t)E * 4);
    uint32* ebuf     = (uint32*)alloc((size_t)E * 4);       // packed (src<<8)|dl
    float* dinv      = (float*)alloc((size_t)n * 4);
    float* stats1    = (float*)alloc(256 * 4);
    float* stats2    = (float*)alloc(128 * 4);
    uint2* xs        = (uint2*)alloc((size_t)n * 16 * 8);   // x*dinv bf16 rows
    __hip_bfloat16* B1 = (__hip_bfloat16*)alloc((size_t)n * 64 * 2);   // AX / hd
    __hip_bfloat16* B2 = (__hip_bfloat16*)alloc((size_t)n * 128 * 2);  // out1/out2

    // param offsets inside Wf
    float* W1f = Wf + 0;     float* b1f = Wf + 8192;
    float* g1f = Wf + 8320;  float* be1f = Wf + 8448;
    float* W2f = Wf + 8576;  float* b2f = Wf + 16768;
    float* g2f = Wf + 16832; float* be2f = Wf + 16896;
    float* W3f = Wf + 16960; float* b3f = Wf + 21056;

    const float invN = 1.0f / (float)n;
    const int nbins = (n + 255) >> 8;        // bins of 256 nodes
    const int ab    = (n + 3) / 4;           // one wave per node, 4 waves/block

    // 1: detect + cvt params + zero stats + bin count (merged, independent)
    setup_cnt_k<<<212, 256, 0, stream>>>((const uint32*)x, flag,
        d_in[2], d_in[3], d_in[4], d_in[5], d_in[6], d_in[7], d_in[8], d_in[9],
        d_in[10], d_in[11], Wf, stats1, stats2, ei + E, pbc, E);
    // 2-4: atomic-free radix CSR build + pre-scaled bf16 xs
    scan2_k<<<1, 256, 0, stream>>>(pbc, bb, row_start + n, E);
    scat_k<<<CB, 256, 0, stream>>>(ei, ei + E, pbc, ebuf, E);
    fill2_k<<<nbins, 256, 0, stream>>>(ebuf, bb, row_start, elist, x, flag,
                                       xs, dinv, n);

    // Layer 1 (aggregate-first): B1 = A_hat x ; out1(B2) = B1@W1 + b1 ; stats1
    agg_k<false, false><<<ab, 256, 0, stream>>>(xs, dinv, row_start, elist,
                                                nullptr, B1, flag, n);
    gemm_k<64, 128, 4, false, true, false><<<(n + 31) / 32, 256, 0, stream>>>(
        B1, W1f, nullptr, nullptr, nullptr, 0.f, b1f, nullptr, B2, n);
    stat_k<64><<<256, 256, 0, stream>>>((const uint2*)B2, stats1, n);

    // Layer 2: hd(B1) = (BN+leaky(out1)@W2)*dinv ; out2(B2) = gather + b2 ; stats2
    gemm_k<128, 64, 4, true, false, true><<<(n + 63) / 64, 256, 0, stream>>>(
        B2, W2f, stats1, g1f, be1f, invN, nullptr, dinv, B1, n);
    agg_k<true, false><<<ab, 256, 0, stream>>>((const uint2*)B1, dinv, row_start,
                                               elist, b2f, B2, flag, n);
    stat_k<32><<<256, 256, 0, stream>>>((const uint2*)B2, stats2, n);

    // Layer 3: hd(B1) = (BN+leaky(out2)@W3)*dinv ; out = gather + b3 (native)
    gemm_k<64, 64, 4, true, false, true><<<(n + 63) / 64, 256, 0, stream>>>(
        B2, W3f, stats2, g2f, be2f, invN, nullptr, dinv, B1, n);
    agg_k<true, true><<<ab, 256, 0, stream>>>((const uint2*)B1, dinv, row_start,
                                              elist, b3f, d_out, flag, n);
}